// Round 10
// baseline (136.928 us; speedup 1.0000x reference)
//
#include <hip/hip_runtime.h>
#include <hip/hip_fp16.h>
#include <cmath>

#define DIM_M 1024   // B (batch)
#define DIM_K 8192   // D
#define DIM_N 4096   // U
#define SPLIT 4
#define KSPL  (DIM_K / SPLIT)   // 2048
#define BKT   32
#define NTT   (KSPL / BKT)      // 64 K-tiles per block
#define NB    1024              // scatter bins
#define EPB   8192              // entries per block in hist/reorder

typedef __attribute__((ext_vector_type(8))) _Float16 half8;
typedef __attribute__((ext_vector_type(4))) float floatx4;

struct __align__(8) Half4 { __half2 a, b; };

__device__ inline void gload_lds16(const void* g, void* l) {
    __builtin_amdgcn_global_load_lds(
        (const __attribute__((address_space(1))) void*)g,
        (__attribute__((address_space(3))) void*)l, 16, 0, 0);
}

__global__ void cvt_f2h(const floatx4* __restrict__ in, Half4* __restrict__ out, int n4) {
    int i = blockIdx.x * blockDim.x + threadIdx.x;
    if (i < n4) {
        floatx4 f = in[i];
        Half4 h;
        h.a = __floats2half2_rn(f.x, f.y);
        h.b = __floats2half2_rn(f.z, f.w);
        out[i] = h;
    }
}

// ---- scatter pipeline: bin -> scan -> reorder(LDS-clustered) -> accumulate --

__global__ __launch_bounds__(512) void hist_k(const int* __restrict__ ind,
                                              unsigned* __restrict__ cnt, int nnz) {
    __shared__ unsigned h[NB];
    const int tid = threadIdx.x;
    for (int i = tid; i < NB; i += 512) h[i] = 0u;
    __syncthreads();
    const int base = blockIdx.x * EPB;
    const int lim = min(nnz - base, EPB);
    const int4* ip = (const int4*)(ind + 2 * (size_t)base);
    for (int k2 = tid; k2 < lim / 2; k2 += 512) {
        int4 w = ip[k2];
        atomicAdd(&h[w.y >> 2], 1u);
        atomicAdd(&h[w.w >> 2], 1u);
    }
    if ((lim & 1) && tid == 0) {
        int u = ind[2 * (size_t)(base + lim - 1) + 1];
        atomicAdd(&h[u >> 2], 1u);
    }
    __syncthreads();
    for (int i = tid; i < NB; i += 512) cnt[(size_t)blockIdx.x * NB + i] = h[i];
}

__global__ void scanb_k(unsigned* cnt, unsigned* __restrict__ bb, int nblk) {
    __shared__ unsigned s[256];
    const int tid = threadIdx.x, bin = blockIdx.x;
    unsigned carry = 0;
    for (int c0 = 0; c0 < nblk; c0 += 256) {
        int b = c0 + tid;
        unsigned v = (b < nblk) ? cnt[(size_t)b * NB + bin] : 0u;
        s[tid] = v;
        __syncthreads();
        for (int off = 1; off < 256; off <<= 1) {
            unsigned add = (tid >= off) ? s[tid - off] : 0u;
            __syncthreads();
            s[tid] += add;
            __syncthreads();
        }
        if (b < nblk) cnt[(size_t)b * NB + bin] = carry + s[tid] - v;
        carry += s[255];
        __syncthreads();
    }
    if (tid == 0) bb[bin] = carry;
}

__global__ void scant_k(unsigned* bb) {
    __shared__ unsigned s[NB];
    const int tid = threadIdx.x;
    unsigned v = bb[tid];
    s[tid] = v;
    __syncthreads();
    for (int off = 1; off < NB; off <<= 1) {
        unsigned add = (tid >= off) ? s[tid - off] : 0u;
        __syncthreads();
        s[tid] += add;
        __syncthreads();
    }
    bb[tid] = s[tid] - v;
    if (tid == NB - 1) bb[NB] = s[tid];
}

__global__ __launch_bounds__(512) void reorder_k(const int* __restrict__ ind,
                                                 const float* __restrict__ kv,
                                                 const unsigned* __restrict__ start,
                                                 const unsigned* __restrict__ bb,
                                                 uint2* __restrict__ ebuf, int nnz) {
    extern __shared__ char rsm[];
    uint2*    buf  = (uint2*)rsm;                 // 64 KB
    unsigned* gofs = (unsigned*)(rsm + 65536);    // 32 KB
    unsigned* cur  = (unsigned*)(rsm + 98304);    //  4 KB
    unsigned* dl   = (unsigned*)(rsm + 102400);   //  4 KB
    unsigned* ss   = (unsigned*)(rsm + 106496);   //  2 KB
    const int tid = threadIdx.x, blk = blockIdx.x;
    const int base = blk * EPB;
    const int lim = min(nnz - base, EPB);
    const int4*   ip = (const int4*)(ind + 2 * (size_t)base);
    const float2* vp = (const float2*)(kv + base);

    for (int i = tid; i < NB; i += 512) cur[i] = 0u;
    __syncthreads();
    for (int k2 = tid; k2 < lim / 2; k2 += 512) {
        int4 w = ip[k2];
        atomicAdd(&cur[w.y >> 2], 1u);
        atomicAdd(&cur[w.w >> 2], 1u);
    }
    if ((lim & 1) && tid == 0) {
        int u = ind[2 * (size_t)(base + lim - 1) + 1];
        atomicAdd(&cur[u >> 2], 1u);
    }
    __syncthreads();
    unsigned c0 = cur[2 * tid], c1 = cur[2 * tid + 1];
    unsigned own = c0 + c1;
    ss[tid] = own;
    __syncthreads();
    for (int off = 1; off < 512; off <<= 1) {
        unsigned t = (tid >= off) ? ss[tid - off] : 0u;
        __syncthreads();
        ss[tid] += t;
        __syncthreads();
    }
    unsigned e0 = ss[tid] - own;
    unsigned e1 = e0 + c0;
    __syncthreads();
    cur[2 * tid]     = e0;
    cur[2 * tid + 1] = e1;
    unsigned g0 = bb[2 * tid]     + start[(size_t)blk * NB + 2 * tid];
    unsigned g1 = bb[2 * tid + 1] + start[(size_t)blk * NB + 2 * tid + 1];
    dl[2 * tid]     = g0 - e0;
    dl[2 * tid + 1] = g1 - e1;
    __syncthreads();
    for (int k2 = tid; k2 < lim / 2; k2 += 512) {
        int4 w = ip[k2];
        float2 v = vp[k2];
        int b0 = w.y >> 2, b1 = w.w >> 2;
        unsigned r0 = atomicAdd(&cur[b0], 1u);
        buf[r0]  = make_uint2(((unsigned)(w.y & 3) << 13) | (unsigned)w.x, __float_as_uint(v.x));
        gofs[r0] = dl[b0] + r0;
        unsigned r1 = atomicAdd(&cur[b1], 1u);
        buf[r1]  = make_uint2(((unsigned)(w.w & 3) << 13) | (unsigned)w.z, __float_as_uint(v.y));
        gofs[r1] = dl[b1] + r1;
    }
    if ((lim & 1) && tid == 0) {
        size_t e = (size_t)base + lim - 1;
        int d = ind[2 * e], u = ind[2 * e + 1];
        int b = u >> 2;
        unsigned r = atomicAdd(&cur[b], 1u);
        buf[r]  = make_uint2(((unsigned)(u & 3) << 13) | (unsigned)d, __float_as_uint(kv[e]));
        gofs[r] = dl[b] + r;
    }
    __syncthreads();
    for (int j = tid; j < lim; j += 512)
        ebuf[gofs[j]] = buf[j];
}

__global__ __launch_bounds__(512) void accum_k(const uint2* __restrict__ ebuf,
                                               const unsigned* __restrict__ bb,
                                               Half4* __restrict__ wh4) {
    extern __shared__ float reg[];            // 128 KB
    floatx4* reg4 = (floatx4*)reg;
    const int tid = threadIdx.x, bin = blockIdx.x;
    for (int i = tid; i < 8192; i += 512) reg4[i] = floatx4{0.f, 0.f, 0.f, 0.f};
    __syncthreads();
    const unsigned s0 = bb[bin], s1 = bb[bin + 1];
    for (unsigned e = s0 + tid; e < s1; e += 512) {
        uint2 p = ebuf[e];
        atomicAdd(&reg[p.x], __uint_as_float(p.y));
    }
    __syncthreads();
    for (int i = tid; i < 8192; i += 512) {
        floatx4 f = reg4[i];
        Half4 h;
        h.a = __floats2half2_rn(f.x, f.y);
        h.b = __floats2half2_rn(f.z, f.w);
        wh4[(size_t)bin * 8192 + i] = h;
    }
}

// ---------------------------------------------------------------------------
// Split-K GEMM restructured for 2 INDEPENDENT blocks per CU (the only
// mechanism that has broken LDS<->MFMA phase-bunching: R1 +65%; intra-block
// scheduling R5/R6/R8 all null). Tile 128x256, BKT=32, 512 thr (8 waves,
// 2Mx4N of 64x64), LDS 2x24KB=48KB -> two co-resident blocks per CU whose
// waves are NOT barrier-synced -> one block's ds_read bursts overlap the
// other's MFMA. Swizzle for 64B rows: chunk ^= (row>>1)&3 (worst 2-way=free).
// ---------------------------------------------------------------------------
__global__ __launch_bounds__(512, 4) void gemm8_k(
    const _Float16* __restrict__ Ah,   // [M][K] fp16
    const _Float16* __restrict__ Bh,   // [N][K] fp16
    _Float16*       __restrict__ part) // [SPLIT][M][N] fp16
{
    __shared__ char smem[2 * 24576];   // buf C: A[128][32] @ C*24576, B[256][32] @ +8192

    const int tid  = threadIdx.x;
    const int lane = tid & 63;
    const int wave = tid >> 6;           // 0..7

    // XCD swizzle: 512 blocks, 8 XCDs, 64 consecutive per XCD.
    // swz = mt(8) | sp(4)<<3 | nt(16)<<5  => each XCD: all mt, all sp, 2 nt.
    const int bid = blockIdx.x;
    const int swz = (bid & 7) * 64 + (bid >> 3);
    const int mt = swz & 7;
    const int sp = (swz >> 3) & 3;
    const int nt = swz >> 5;
    const int m0 = mt * 128;
    const int n0 = nt * 256;
    const size_t kbase = (size_t)sp * KSPL;

    // staging: row = tid>>2 (0..127), phys chunk = tid&3,
    // source logical chunk = (tid&3) ^ ((row>>1)&3) = (tid&3) ^ ((tid>>3)&3)
    const int srow = tid >> 2;
    const int sch  = (tid & 3) ^ ((tid >> 3) & 3);
    const _Float16* aSg = Ah + (size_t)(m0 + srow) * DIM_K + kbase + sch * 8;
    const _Float16* bSg0 = Bh + (size_t)(n0 + srow) * DIM_K + kbase + sch * 8;
    const _Float16* bSg1 = Bh + (size_t)(n0 + 128 + srow) * DIM_K + kbase + sch * 8;
    char* aL  = smem + wave * 1024;
    char* bL0 = smem + 8192 + wave * 1024;
    char* bL1 = smem + 16384 + wave * 1024;

    // read side: wave (wrm 0..1, wn 0..3), 64x64 tile; row&6 bits give swizzle
    const int wrm = wave >> 2;
    const int wn  = wave & 3;
    const int q   = lane >> 4;
    const char* aRd = smem + (wrm * 64 + (lane & 15)) * 64;
    const char* bRd = smem + 8192 + (wn * 64 + (lane & 15)) * 64;
    const int ch = ((lane >> 4) ^ ((lane >> 1) & 3)) * 16;

    floatx4 acc[4][4] = {};
    half8 aF[4], bF[4];

#define STAGE(C)                                                              \
    { gload_lds16(aSg,  aL  + (C) * 24576);                                   \
      gload_lds16(bSg0, bL0 + (C) * 24576);                                   \
      gload_lds16(bSg1, bL1 + (C) * 24576);                                   \
      aSg += BKT; bSg0 += BKT; bSg1 += BKT; }

#define KTILE(C)                                                              \
    { _Pragma("unroll") for (int i = 0; i < 4; ++i)                           \
        aF[i] = *(const half8*)(aRd + (C) * 24576 + i * 1024 + ch);           \
      _Pragma("unroll") for (int i = 0; i < 4; ++i)                           \
        bF[i] = *(const half8*)(bRd + (C) * 24576 + i * 1024 + ch);           \
      asm volatile("s_waitcnt lgkmcnt(0)" ::: "memory");                      \
      __builtin_amdgcn_sched_barrier(0);                                      \
      __builtin_amdgcn_s_setprio(1);                                          \
      _Pragma("unroll") for (int mi = 0; mi < 4; ++mi)                        \
        _Pragma("unroll") for (int ni = 0; ni < 4; ++ni)                      \
          acc[mi][ni] = __builtin_amdgcn_mfma_f32_16x16x32_f16(               \
              aF[mi], bF[ni], acc[mi][ni], 0, 0, 0);                          \
      __builtin_amdgcn_s_setprio(0); }

    // prologue: stage K-tiles 0,1 (3 loads each); wait tile 0
    STAGE(0)
    STAGE(1)
    asm volatile("s_waitcnt vmcnt(3)" ::: "memory");
    __builtin_amdgcn_s_barrier();

    for (int t2 = 0; t2 < NTT / 2; ++t2) {
        KTILE(0)                                  // compute tile 2*t2 (buf0)
        __builtin_amdgcn_s_barrier();             // all waves done reading buf0
        if (t2 < NTT / 2 - 1) {
            STAGE(0)                              // stage tile 2*t2+2 into buf0
            asm volatile("s_waitcnt vmcnt(3)" ::: "memory");  // tile 2*t2+1 landed
        } else {
            asm volatile("s_waitcnt vmcnt(0)" ::: "memory");  // last tile landed
        }
        __builtin_amdgcn_s_barrier();
        KTILE(1)                                  // compute tile 2*t2+1 (buf1)
        if (t2 < NTT / 2 - 1) {
            __builtin_amdgcn_s_barrier();         // all waves done reading buf1
            STAGE(1)                              // stage tile 2*t2+3 into buf1
            asm volatile("s_waitcnt vmcnt(3)" ::: "memory");  // tile 2*t2+2 landed
            __builtin_amdgcn_s_barrier();
        }
    }

#undef KTILE
#undef STAGE

    // epilogue: fp16 partials (C/D layout: col = lane&15, row = q*4 + r)
    _Float16* pbase = part + (size_t)sp * DIM_M * DIM_N;
    #pragma unroll
    for (int ni = 0; ni < 4; ++ni) {
        const int col = n0 + wn * 64 + ni * 16 + (lane & 15);
        #pragma unroll
        for (int mi = 0; mi < 4; ++mi) {
            const int row = m0 + wrm * 64 + mi * 16 + (q << 2);
            #pragma unroll
            for (int r = 0; r < 4; ++r)
                pbase[(size_t)(row + r) * DIM_N + col] = (_Float16)acc[mi][ni][r];
        }
    }
}

// out = tanh(sum_splits(fp16 part) + bias), 4 outputs/thread
__global__ void reduce_tanh(const Half4* __restrict__ part, const float* __restrict__ bias,
                            floatx4* __restrict__ out) {
    const int n4 = DIM_M * DIM_N / 4;
    int i = blockIdx.x * blockDim.x + threadIdx.x;
    if (i < n4) {
        float sx = 0.f, sy = 0.f, sz = 0.f, sw = 0.f;
        #pragma unroll
        for (int sp = 0; sp < SPLIT; ++sp) {
            Half4 p = part[(size_t)sp * n4 + i];
            float2 lo = __half22float2(p.a);
            float2 hi = __half22float2(p.b);
            sx += lo.x; sy += lo.y; sz += hi.x; sw += hi.y;
        }
        floatx4 b = ((const floatx4*)bias)[i & (DIM_N / 4 - 1)];
        floatx4 o;
        o.x = tanhf(sx + b.x);
        o.y = tanhf(sy + b.y);
        o.z = tanhf(sz + b.z);
        o.w = tanhf(sw + b.w);
        out[i] = o;
    }
}

extern "C" void kernel_launch(void* const* d_in, const int* in_sizes, int n_in,
                              void* d_out, int out_size, void* d_ws, size_t ws_size,
                              hipStream_t stream) {
    const float* x    = (const float*)d_in[0];
    const float* kv   = (const float*)d_in[1];
    const float* bias = (const float*)d_in[2];
    const int*   ind  = (const int*)d_in[3];
    float* out = (float*)d_out;
    const int nnz = in_sizes[1];

    char* ws = (char*)d_ws;
    _Float16* wh = (_Float16*)ws;                               // [N][K] fp16, 64 MB
    const size_t whBytes = (size_t)DIM_N * DIM_K * 2;
    _Float16* xh = (_Float16*)(ws + whBytes);                   // [M][K] fp16, 16 MB
    const size_t xhBytes = (size_t)DIM_M * DIM_K * 2;
    _Float16* part = (_Float16*)(ws + whBytes + xhBytes);       // [SPLIT][M][N] fp16, 32 MB
    const size_t partBytes = (size_t)SPLIT * DIM_M * DIM_N * 2;
    uint2* ebuf = (uint2*)(ws + whBytes + xhBytes + partBytes); // nnz*8 B (<=16 MB)
    const size_t ebufBytes = (size_t)16 << 20;
    unsigned* cnt = (unsigned*)(ws + whBytes + xhBytes + partBytes + ebufBytes); // 4 MB
    const size_t cntBytes = (size_t)1024 * NB * 4;
    unsigned* bb = (unsigned*)(ws + whBytes + xhBytes + partBytes + ebufBytes + cntBytes); // NB+1

    const int xN4 = (int)((size_t)DIM_M * DIM_K / 4);
    const int oN4 = DIM_M * DIM_N / 4;
    const int nblk = (nnz + EPB - 1) / EPB;

    cvt_f2h<<<(xN4 + 255) / 256, 256, 0, stream>>>((const floatx4*)x, (Half4*)xh, xN4);
    hist_k<<<nblk, 512, 0, stream>>>(ind, cnt, nnz);
    scanb_k<<<NB, 256, 0, stream>>>(cnt, bb, nblk);
    scant_k<<<1, NB, 0, stream>>>(bb);

    hipFuncSetAttribute((const void*)reorder_k,
                        hipFuncAttributeMaxDynamicSharedMemorySize, 131072);
    reorder_k<<<nblk, 512, 110592, stream>>>(ind, kv, cnt, bb, ebuf, nnz);

    hipFuncSetAttribute((const void*)accum_k,
                        hipFuncAttributeMaxDynamicSharedMemorySize, 131072);
    accum_k<<<NB, 512, 131072, stream>>>(ebuf, bb, (Half4*)wh);

    gemm8_k<<<dim3(512), 512, 0, stream>>>(xh, wh, part);

    reduce_tanh<<<(oN4 + 255) / 256, 256, 0, stream>>>((const Half4*)part, bias, (floatx4*)out);
}

// Round 11
// 135.854 us; speedup vs baseline: 1.0079x; 1.0079x over previous
//
#include <hip/hip_runtime.h>
#include <hip/hip_fp16.h>
#include <cmath>

#define DIM_M 1024   // B (batch)
#define DIM_K 8192   // D
#define DIM_N 4096   // U
#define SPLIT 4
#define KSPL  (DIM_K / SPLIT)   // 2048
#define BKT   32
#define NTT   (KSPL / BKT)      // 64 K-tiles per block
#define NB    1024              // scatter bins
#define EPB   8192              // entries per block in hist/reorder

typedef __attribute__((ext_vector_type(8))) _Float16 half8;
typedef __attribute__((ext_vector_type(4))) float floatx4;

struct __align__(8) Half4 { __half2 a, b; };

__device__ inline void gload_lds16(const void* g, void* l) {
    __builtin_amdgcn_global_load_lds(
        (const __attribute__((address_space(1))) void*)g,
        (__attribute__((address_space(3))) void*)l, 16, 0, 0);
}

__global__ void cvt_f2h(const floatx4* __restrict__ in, Half4* __restrict__ out, int n4) {
    int i = blockIdx.x * blockDim.x + threadIdx.x;
    if (i < n4) {
        floatx4 f = in[i];
        Half4 h;
        h.a = __floats2half2_rn(f.x, f.y);
        h.b = __floats2half2_rn(f.z, f.w);
        out[i] = h;
    }
}

// ---- scatter pipeline: bin -> scan -> reorder(LDS-clustered) -> accumulate --

__global__ __launch_bounds__(512) void hist_k(const int* __restrict__ ind,
                                              unsigned* __restrict__ cnt, int nnz) {
    __shared__ unsigned h[NB];
    const int tid = threadIdx.x;
    for (int i = tid; i < NB; i += 512) h[i] = 0u;
    __syncthreads();
    const int base = blockIdx.x * EPB;
    const int lim = min(nnz - base, EPB);
    const int4* ip = (const int4*)(ind + 2 * (size_t)base);
    for (int k2 = tid; k2 < lim / 2; k2 += 512) {
        int4 w = ip[k2];
        atomicAdd(&h[w.y >> 2], 1u);
        atomicAdd(&h[w.w >> 2], 1u);
    }
    if ((lim & 1) && tid == 0) {
        int u = ind[2 * (size_t)(base + lim - 1) + 1];
        atomicAdd(&h[u >> 2], 1u);
    }
    __syncthreads();
    for (int i = tid; i < NB; i += 512) cnt[(size_t)blockIdx.x * NB + i] = h[i];
}

__global__ void scanb_k(unsigned* cnt, unsigned* __restrict__ bb, int nblk) {
    __shared__ unsigned s[256];
    const int tid = threadIdx.x, bin = blockIdx.x;
    unsigned carry = 0;
    for (int c0 = 0; c0 < nblk; c0 += 256) {
        int b = c0 + tid;
        unsigned v = (b < nblk) ? cnt[(size_t)b * NB + bin] : 0u;
        s[tid] = v;
        __syncthreads();
        for (int off = 1; off < 256; off <<= 1) {
            unsigned add = (tid >= off) ? s[tid - off] : 0u;
            __syncthreads();
            s[tid] += add;
            __syncthreads();
        }
        if (b < nblk) cnt[(size_t)b * NB + bin] = carry + s[tid] - v;
        carry += s[255];
        __syncthreads();
    }
    if (tid == 0) bb[bin] = carry;
}

__global__ void scant_k(unsigned* bb) {
    __shared__ unsigned s[NB];
    const int tid = threadIdx.x;
    unsigned v = bb[tid];
    s[tid] = v;
    __syncthreads();
    for (int off = 1; off < NB; off <<= 1) {
        unsigned add = (tid >= off) ? s[tid - off] : 0u;
        __syncthreads();
        s[tid] += add;
        __syncthreads();
    }
    bb[tid] = s[tid] - v;
    if (tid == NB - 1) bb[NB] = s[tid];
}

__global__ __launch_bounds__(512) void reorder_k(const int* __restrict__ ind,
                                                 const float* __restrict__ kv,
                                                 const unsigned* __restrict__ start,
                                                 const unsigned* __restrict__ bb,
                                                 uint2* __restrict__ ebuf, int nnz) {
    extern __shared__ char rsm[];
    uint2*    buf  = (uint2*)rsm;                 // 64 KB
    unsigned* gofs = (unsigned*)(rsm + 65536);    // 32 KB
    unsigned* cur  = (unsigned*)(rsm + 98304);    //  4 KB
    unsigned* dl   = (unsigned*)(rsm + 102400);   //  4 KB
    unsigned* ss   = (unsigned*)(rsm + 106496);   //  2 KB
    const int tid = threadIdx.x, blk = blockIdx.x;
    const int base = blk * EPB;
    const int lim = min(nnz - base, EPB);
    const int4*   ip = (const int4*)(ind + 2 * (size_t)base);
    const float2* vp = (const float2*)(kv + base);

    for (int i = tid; i < NB; i += 512) cur[i] = 0u;
    __syncthreads();
    for (int k2 = tid; k2 < lim / 2; k2 += 512) {
        int4 w = ip[k2];
        atomicAdd(&cur[w.y >> 2], 1u);
        atomicAdd(&cur[w.w >> 2], 1u);
    }
    if ((lim & 1) && tid == 0) {
        int u = ind[2 * (size_t)(base + lim - 1) + 1];
        atomicAdd(&cur[u >> 2], 1u);
    }
    __syncthreads();
    unsigned c0 = cur[2 * tid], c1 = cur[2 * tid + 1];
    unsigned own = c0 + c1;
    ss[tid] = own;
    __syncthreads();
    for (int off = 1; off < 512; off <<= 1) {
        unsigned t = (tid >= off) ? ss[tid - off] : 0u;
        __syncthreads();
        ss[tid] += t;
        __syncthreads();
    }
    unsigned e0 = ss[tid] - own;
    unsigned e1 = e0 + c0;
    __syncthreads();
    cur[2 * tid]     = e0;
    cur[2 * tid + 1] = e1;
    unsigned g0 = bb[2 * tid]     + start[(size_t)blk * NB + 2 * tid];
    unsigned g1 = bb[2 * tid + 1] + start[(size_t)blk * NB + 2 * tid + 1];
    dl[2 * tid]     = g0 - e0;
    dl[2 * tid + 1] = g1 - e1;
    __syncthreads();
    for (int k2 = tid; k2 < lim / 2; k2 += 512) {
        int4 w = ip[k2];
        float2 v = vp[k2];
        int b0 = w.y >> 2, b1 = w.w >> 2;
        unsigned r0 = atomicAdd(&cur[b0], 1u);
        buf[r0]  = make_uint2(((unsigned)(w.y & 3) << 13) | (unsigned)w.x, __float_as_uint(v.x));
        gofs[r0] = dl[b0] + r0;
        unsigned r1 = atomicAdd(&cur[b1], 1u);
        buf[r1]  = make_uint2(((unsigned)(w.w & 3) << 13) | (unsigned)w.z, __float_as_uint(v.y));
        gofs[r1] = dl[b1] + r1;
    }
    if ((lim & 1) && tid == 0) {
        size_t e = (size_t)base + lim - 1;
        int d = ind[2 * e], u = ind[2 * e + 1];
        int b = u >> 2;
        unsigned r = atomicAdd(&cur[b], 1u);
        buf[r]  = make_uint2(((unsigned)(u & 3) << 13) | (unsigned)d, __float_as_uint(kv[e]));
        gofs[r] = dl[b] + r;
    }
    __syncthreads();
    for (int j = tid; j < lim; j += 512)
        ebuf[gofs[j]] = buf[j];
}

__global__ __launch_bounds__(512) void accum_k(const uint2* __restrict__ ebuf,
                                               const unsigned* __restrict__ bb,
                                               Half4* __restrict__ wh4) {
    extern __shared__ float reg[];            // 128 KB
    floatx4* reg4 = (floatx4*)reg;
    const int tid = threadIdx.x, bin = blockIdx.x;
    for (int i = tid; i < 8192; i += 512) reg4[i] = floatx4{0.f, 0.f, 0.f, 0.f};
    __syncthreads();
    const unsigned s0 = bb[bin], s1 = bb[bin + 1];
    for (unsigned e = s0 + tid; e < s1; e += 512) {
        uint2 p = ebuf[e];
        atomicAdd(&reg[p.x], __uint_as_float(p.y));
    }
    __syncthreads();
    for (int i = tid; i < 8192; i += 512) {
        floatx4 f = reg4[i];
        Half4 h;
        h.a = __floats2half2_rn(f.x, f.y);
        h.b = __floats2half2_rn(f.z, f.w);
        wh4[(size_t)bin * 8192 + i] = h;
    }
}

// ---------------------------------------------------------------------------
// Faithful m201-style schedule (the fine per-phase interleave m196 proved is
// THE lever; coarse tile-batched staging costs -7..-27%). 256x256 tile,
// BKT=32, ring-4 LDS buffers (4 x (A16KB+B16KB) = 128KB), 8 waves of 128x64
// (12 ds_read per 32 MFMA per K-tile). Per K-tile = 2 phases, each:
//   {ds_read 8|4 , 2 x global_load_lds(tile t+3)} barrier lgkm(0) 16 MFMA barrier
// with counted vmcnt(8) ONCE per tile after MFMA (3 tiles in flight, never
// drained in the loop). MFMA pipe backlog drains during the next phase's
// read/stage burst -> LDS port and matrix pipe both stay fed.
// Tail staging overruns K-slice bounds harmlessly (lands in adjacent ws
// buffers, never consumed).
// ---------------------------------------------------------------------------
__global__ __launch_bounds__(512, 2) void gemm8_k(
    const _Float16* __restrict__ Ah,   // [M][K] fp16
    const _Float16* __restrict__ Bh,   // [N][K] fp16
    _Float16*       __restrict__ part) // [SPLIT][M][N] fp16
{
    extern __shared__ char smem[];     // ring buf c: A[256][32] @ c*32768, B @ +16384

    const int tid  = threadIdx.x;
    const int lane = tid & 63;
    const int wave = tid >> 6;           // 0..7

    const int bid = blockIdx.x;
    const int swz = (bid & 7) * 32 + (bid >> 3);
    const int n0  = (swz >> 4) * 256;
    const int rem = swz & 15;
    const int m0  = (rem >> 2) * 256;
    const int sp  = rem & 3;
    const size_t kbase = (size_t)sp * KSPL;

    // staging: row = tid>>2, phys chunk = tid&3, src chunk ^= (row>>1)&3
    const int srow = tid >> 2;                   // 0..127
    const int sch  = (tid & 3) ^ ((tid >> 3) & 3);
    const _Float16* aSg = Ah + (size_t)(m0 + srow) * DIM_K + kbase + sch * 8;
    const _Float16* bSg = Bh + (size_t)(n0 + srow) * DIM_K + kbase + sch * 8;
    const int wofs = wave * 1024;

    // read side: wave tile 128x64 (wrm = M half, wn = N quarter)
    const int wrm = wave >> 2;
    const int wn  = wave & 3;
    const int q   = lane >> 4;
    const char* aRd = smem + (wrm * 128 + (lane & 15)) * 64;
    const char* bRd = smem + 16384 + (wn * 64 + (lane & 15)) * 64;
    const int ch = (q ^ ((lane >> 1) & 3)) * 16;

    floatx4 acc[8][4] = {};
    half8 aF[4], bF[4];

#define STA(SB)                                                               \
    { gload_lds16(aSg,                         smem + (SB) * 32768 + wofs);   \
      gload_lds16(aSg + (size_t)128 * DIM_K,   smem + (SB) * 32768 + 8192 + wofs); }
#define STB(SB)                                                               \
    { gload_lds16(bSg,                         smem + (SB) * 32768 + 16384 + wofs); \
      gload_lds16(bSg + (size_t)128 * DIM_K,   smem + (SB) * 32768 + 24576 + wofs); }
#define ADV() { aSg += BKT; bSg += BKT; }

// Phase 0: read A mi0-3 + B, stage A of tile t+3; MFMA quadrant 0
#define PH0(CB, SB)                                                           \
    { _Pragma("unroll") for (int i = 0; i < 4; ++i)                           \
        aF[i] = *(const half8*)(aRd + (CB) * 32768 + i * 1024 + ch);          \
      _Pragma("unroll") for (int i = 0; i < 4; ++i)                           \
        bF[i] = *(const half8*)(bRd + (CB) * 32768 + i * 1024 + ch);          \
      STA(SB)                                                                 \
      __builtin_amdgcn_s_barrier();                                           \
      asm volatile("s_waitcnt lgkmcnt(0)" ::: "memory");                      \
      __builtin_amdgcn_sched_barrier(0);                                      \
      __builtin_amdgcn_s_setprio(1);                                          \
      _Pragma("unroll") for (int mi = 0; mi < 4; ++mi)                        \
        _Pragma("unroll") for (int ni = 0; ni < 4; ++ni)                      \
          acc[mi][ni] = __builtin_amdgcn_mfma_f32_16x16x32_f16(               \
              aF[mi], bF[ni], acc[mi][ni], 0, 0, 0);                          \
      __builtin_amdgcn_s_setprio(0);                                          \
      __builtin_amdgcn_s_barrier(); }

// Phase 1: read A mi4-7, stage B of tile t+3; MFMA quadrant 1; tile-boundary vmcnt(8)
#define PH1(CB, SB)                                                           \
    { _Pragma("unroll") for (int i = 0; i < 4; ++i)                           \
        aF[i] = *(const half8*)(aRd + (CB) * 32768 + 4096 + i * 1024 + ch);   \
      STB(SB) ADV()                                                           \
      __builtin_amdgcn_s_barrier();                                           \
      asm volatile("s_waitcnt lgkmcnt(0)" ::: "memory");                      \
      __builtin_amdgcn_sched_barrier(0);                                      \
      __builtin_amdgcn_s_setprio(1);                                          \
      _Pragma("unroll") for (int mi = 0; mi < 4; ++mi)                        \
        _Pragma("unroll") for (int ni = 0; ni < 4; ++ni)                      \
          acc[4 + mi][ni] = __builtin_amdgcn_mfma_f32_16x16x32_f16(           \
              aF[mi], bF[ni], acc[4 + mi][ni], 0, 0, 0);                      \
      __builtin_amdgcn_s_setprio(0);                                          \
      asm volatile("s_waitcnt vmcnt(8)" ::: "memory");                        \
      __builtin_amdgcn_s_barrier(); }

#define KTILE(CB, SB) PH0(CB, SB) PH1(CB, SB)

    // prologue: stage tiles 0,1,2 (4 gloads each); T0 landed when vmcnt<=8
    STA(0) STB(0) ADV()
    STA(1) STB(1) ADV()
    STA(2) STB(2) ADV()
    asm volatile("s_waitcnt vmcnt(8)" ::: "memory");
    __builtin_amdgcn_s_barrier();

    for (int it = 0; it < NTT / 4; ++it) {
        KTILE(0, 3)   // compute tile 4it+0 (buf0), stage tile 4it+3 -> buf3
        KTILE(1, 0)
        KTILE(2, 1)
        KTILE(3, 2)
    }

#undef KTILE
#undef PH1
#undef PH0
#undef ADV
#undef STB
#undef STA

    // epilogue: fp16 partials (C/D layout: col = lane&15, row = q*4 + r)
    _Float16* pbase = part + (size_t)sp * DIM_M * DIM_N;
    #pragma unroll
    for (int ni = 0; ni < 4; ++ni) {
        const int col = n0 + wn * 64 + ni * 16 + (lane & 15);
        #pragma unroll
        for (int mi = 0; mi < 8; ++mi) {
            const int row = m0 + wrm * 128 + mi * 16 + (q << 2);
            #pragma unroll
            for (int r = 0; r < 4; ++r)
                pbase[(size_t)(row + r) * DIM_N + col] = (_Float16)acc[mi][ni][r];
        }
    }
}

// out = tanh(sum_splits(fp16 part) + bias), 4 outputs/thread
__global__ void reduce_tanh(const Half4* __restrict__ part, const float* __restrict__ bias,
                            floatx4* __restrict__ out) {
    const int n4 = DIM_M * DIM_N / 4;
    int i = blockIdx.x * blockDim.x + threadIdx.x;
    if (i < n4) {
        float sx = 0.f, sy = 0.f, sz = 0.f, sw = 0.f;
        #pragma unroll
        for (int sp = 0; sp < SPLIT; ++sp) {
            Half4 p = part[(size_t)sp * n4 + i];
            float2 lo = __half22float2(p.a);
            float2 hi = __half22float2(p.b);
            sx += lo.x; sy += lo.y; sz += hi.x; sw += hi.y;
        }
        floatx4 b = ((const floatx4*)bias)[i & (DIM_N / 4 - 1)];
        floatx4 o;
        o.x = tanhf(sx + b.x);
        o.y = tanhf(sy + b.y);
        o.z = tanhf(sz + b.z);
        o.w = tanhf(sw + b.w);
        out[i] = o;
    }
}

extern "C" void kernel_launch(void* const* d_in, const int* in_sizes, int n_in,
                              void* d_out, int out_size, void* d_ws, size_t ws_size,
                              hipStream_t stream) {
    const float* x    = (const float*)d_in[0];
    const float* kv   = (const float*)d_in[1];
    const float* bias = (const float*)d_in[2];
    const int*   ind  = (const int*)d_in[3];
    float* out = (float*)d_out;
    const int nnz = in_sizes[1];

    char* ws = (char*)d_ws;
    _Float16* wh = (_Float16*)ws;                               // [N][K] fp16, 64 MB
    const size_t whBytes = (size_t)DIM_N * DIM_K * 2;
    _Float16* xh = (_Float16*)(ws + whBytes);                   // [M][K] fp16, 16 MB
    const size_t xhBytes = (size_t)DIM_M * DIM_K * 2;
    _Float16* part = (_Float16*)(ws + whBytes + xhBytes);       // [SPLIT][M][N] fp16, 32 MB
    const size_t partBytes = (size_t)SPLIT * DIM_M * DIM_N * 2;
    uint2* ebuf = (uint2*)(ws + whBytes + xhBytes + partBytes); // nnz*8 B (<=16 MB)
    const size_t ebufBytes = (size_t)16 << 20;
    unsigned* cnt = (unsigned*)(ws + whBytes + xhBytes + partBytes + ebufBytes); // 4 MB
    const size_t cntBytes = (size_t)1024 * NB * 4;
    unsigned* bb = (unsigned*)(ws + whBytes + xhBytes + partBytes + ebufBytes + cntBytes); // NB+1

    const int xN4 = (int)((size_t)DIM_M * DIM_K / 4);
    const int oN4 = DIM_M * DIM_N / 4;
    const int nblk = (nnz + EPB - 1) / EPB;

    cvt_f2h<<<(xN4 + 255) / 256, 256, 0, stream>>>((const floatx4*)x, (Half4*)xh, xN4);
    hist_k<<<nblk, 512, 0, stream>>>(ind, cnt, nnz);
    scanb_k<<<NB, 256, 0, stream>>>(cnt, bb, nblk);
    scant_k<<<1, NB, 0, stream>>>(bb);

    hipFuncSetAttribute((const void*)reorder_k,
                        hipFuncAttributeMaxDynamicSharedMemorySize, 131072);
    reorder_k<<<nblk, 512, 110592, stream>>>(ind, kv, cnt, bb, ebuf, nnz);

    hipFuncSetAttribute((const void*)accum_k,
                        hipFuncAttributeMaxDynamicSharedMemorySize, 131072);
    accum_k<<<NB, 512, 131072, stream>>>(ebuf, bb, (Half4*)wh);

    hipFuncSetAttribute((const void*)gemm8_k,
                        hipFuncAttributeMaxDynamicSharedMemorySize, 131072);
    gemm8_k<<<dim3(256), 512, 131072, stream>>>(xh, wh, part);

    reduce_tanh<<<(oN4 + 255) / 256, 256, 0, stream>>>((const Half4*)part, bias, (floatx4*)out);
}